// Round 1
// baseline (7831.863 us; speedup 1.0000x reference)
//
#include <hip/hip_runtime.h>

#define THREADS 256

// Detect whether edge_index arrived as int64 (high words zero) or int32.
// Deterministic: depends only on input data.
__global__ void detect_i64_kernel(const int* __restrict__ e, int* __restrict__ flag) {
    if (blockIdx.x == 0 && threadIdx.x == 0) {
        bool all_odd_zero = true, any_even = false;
#pragma unroll
        for (int k = 0; k < 16; ++k) {
            if (e[2 * k + 1] != 0) all_odd_zero = false;
            if (e[2 * k] != 0) any_even = true;
        }
        *flag = (all_odd_zero && any_even) ? 1 : 0;
    }
}

// deg[dst] += 1 over all edges (self-loop added later as +1)
__global__ void deg_kernel(const int* __restrict__ e, long long E,
                           const int* __restrict__ flag, float* __restrict__ deg) {
    const bool i64 = (*flag != 0);
    long long i = (long long)blockIdx.x * blockDim.x + threadIdx.x;
    const long long stride = (long long)gridDim.x * blockDim.x;
    for (; i < E; i += stride) {
        long long t = i64 ? (long long)e[2 * E + 2 * i] : (long long)e[E + i];
        atomicAdd(deg + t, 1.0f);
    }
}

// dinv = rsqrt(deg+1) (in place over deg); y1 = x * dinv * W1  (W1: [1,3])
__global__ void node_init_kernel(const float* __restrict__ x, const float* __restrict__ W1,
                                 float* __restrict__ deg_dinv, float* __restrict__ A, int N) {
    int i = blockIdx.x * blockDim.x + threadIdx.x;
    if (i >= N) return;
    float di = rsqrtf(deg_dinv[i] + 1.0f);
    deg_dinv[i] = di;
    float v = x[i] * di;
    A[i * 3 + 0] = v * W1[0];
    A[i * 3 + 1] = v * W1[1];
    A[i * 3 + 2] = v * W1[2];
}

// acc[dst] += y[src]  (dinv[src] already folded into y)
__global__ void scatter_kernel(const int* __restrict__ e, long long E,
                               const int* __restrict__ flag,
                               const float* __restrict__ y, float* __restrict__ acc) {
    const bool i64 = (*flag != 0);
    long long i = (long long)blockIdx.x * blockDim.x + threadIdx.x;
    const long long stride = (long long)gridDim.x * blockDim.x;
    for (; i < E; i += stride) {
        long long s, t;
        if (i64) { s = e[2 * i]; t = e[2 * E + 2 * i]; }
        else     { s = e[i];     t = e[E + i]; }
        float y0 = y[s * 3 + 0];
        float y1 = y[s * 3 + 1];
        float y2 = y[s * 3 + 2];
        atomicAdd(acc + t * 3 + 0, y0);
        atomicAdd(acc + t * 3 + 1, y1);
        atomicAdd(acc + t * 3 + 2, y2);
    }
}

// h = relu(dinv*(acc + y) + b); ynext = dinv * (h @ Wn); write ynext over acc (in place)
__global__ void finalize_mid_kernel(const float* __restrict__ dinv, const float* __restrict__ y,
                                    float* __restrict__ acc, const float* __restrict__ b,
                                    const float* __restrict__ Wn, int N) {
    int i = blockIdx.x * blockDim.x + threadIdx.x;
    if (i >= N) return;
    float di = dinv[i];
    float h0 = fmaxf(di * (acc[i * 3 + 0] + y[i * 3 + 0]) + b[0], 0.0f);
    float h1 = fmaxf(di * (acc[i * 3 + 1] + y[i * 3 + 1]) + b[1], 0.0f);
    float h2 = fmaxf(di * (acc[i * 3 + 2] + y[i * 3 + 2]) + b[2], 0.0f);
    // Wn: [3,3] row-major [k][c]; z[c] = sum_k h[k]*Wn[k*3+c]
    float z0 = di * (h0 * Wn[0] + h1 * Wn[3] + h2 * Wn[6]);
    float z1 = di * (h0 * Wn[1] + h1 * Wn[4] + h2 * Wn[7]);
    float z2 = di * (h0 * Wn[2] + h1 * Wn[5] + h2 * Wn[8]);
    acc[i * 3 + 0] = z0;
    acc[i * 3 + 1] = z1;
    acc[i * 3 + 2] = z2;
}

// out = relu(dinv*(acc + y) + b)
__global__ void finalize_last_kernel(const float* __restrict__ dinv, const float* __restrict__ y,
                                     const float* __restrict__ acc, const float* __restrict__ b,
                                     float* __restrict__ out, int N) {
    int i = blockIdx.x * blockDim.x + threadIdx.x;
    if (i >= N) return;
    float di = dinv[i];
    out[i * 3 + 0] = fmaxf(di * (acc[i * 3 + 0] + y[i * 3 + 0]) + b[0], 0.0f);
    out[i * 3 + 1] = fmaxf(di * (acc[i * 3 + 1] + y[i * 3 + 1]) + b[1], 0.0f);
    out[i * 3 + 2] = fmaxf(di * (acc[i * 3 + 2] + y[i * 3 + 2]) + b[2], 0.0f);
}

extern "C" void kernel_launch(void* const* d_in, const int* in_sizes, int n_in,
                              void* d_out, int out_size, void* d_ws, size_t ws_size,
                              hipStream_t stream) {
    const float* x  = (const float*)d_in[0];
    const int*   ei = (const int*)d_in[1];
    const float* W1 = (const float*)d_in[2];
    const float* b1 = (const float*)d_in[3];
    const float* W2 = (const float*)d_in[4];
    const float* b2 = (const float*)d_in[5];
    const float* W3 = (const float*)d_in[6];
    const float* b3 = (const float*)d_in[7];
    float* out = (float*)d_out;

    const long long N = in_sizes[0];        // x is [N,1]
    const long long E = (long long)in_sizes[1] / 2;

    char* w = (char*)d_ws;
    int*   flag = (int*)w;
    float* dinv = (float*)(w + 256);
    float* A    = dinv + N;
    size_t need_full = 256 + (size_t)N * 4 + (size_t)N * 12 * 2;
    float* B = (ws_size >= need_full) ? (A + 3 * N) : out;

    const int nblk = (int)((N + THREADS - 1) / THREADS);
    const int eblk = 2048;  // grid-stride over edges

    detect_i64_kernel<<<1, 64, 0, stream>>>(ei, flag);

    hipMemsetAsync(dinv, 0, (size_t)N * 4, stream);
    deg_kernel<<<eblk, THREADS, 0, stream>>>(ei, E, flag, dinv);
    node_init_kernel<<<nblk, THREADS, 0, stream>>>(x, W1, dinv, A, (int)N);

    // layer 1: scatter A -> B, finalize writes y2 into B
    hipMemsetAsync(B, 0, (size_t)N * 12, stream);
    scatter_kernel<<<eblk, THREADS, 0, stream>>>(ei, E, flag, A, B);
    finalize_mid_kernel<<<nblk, THREADS, 0, stream>>>(dinv, A, B, b1, W2, (int)N);

    // layer 2: scatter B -> A, finalize writes y3 into A
    hipMemsetAsync(A, 0, (size_t)N * 12, stream);
    scatter_kernel<<<eblk, THREADS, 0, stream>>>(ei, E, flag, B, A);
    finalize_mid_kernel<<<nblk, THREADS, 0, stream>>>(dinv, B, A, b2, W3, (int)N);

    // layer 3: scatter A -> B, finalize to out (B may alias out; in-place safe)
    hipMemsetAsync(B, 0, (size_t)N * 12, stream);
    scatter_kernel<<<eblk, THREADS, 0, stream>>>(ei, E, flag, A, B);
    finalize_last_kernel<<<nblk, THREADS, 0, stream>>>(dinv, A, B, b3, out, (int)N);
}

// Round 2
// 2259.546 us; speedup vs baseline: 3.4661x; 3.4661x over previous
//
#include <hip/hip_runtime.h>

#define THREADS 256
#define SCAN_TPB 256
#define SCAN_ELEMS 4096   // 16 elems per thread * 256 threads

// ---------------- common ----------------

__global__ void detect_i64_kernel(const int* __restrict__ e, int* __restrict__ flag) {
    if (blockIdx.x == 0 && threadIdx.x == 0) {
        bool all_odd_zero = true, any_even = false;
#pragma unroll
        for (int k = 0; k < 16; ++k) {
            if (e[2 * k + 1] != 0) all_odd_zero = false;
            if (e[2 * k] != 0) any_even = true;
        }
        *flag = (all_odd_zero && any_even) ? 1 : 0;
    }
}

__device__ __forceinline__ void edge_sd(const int* __restrict__ e, long long E, bool i64,
                                        long long i, int& s, int& t) {
    if (i64) { s = e[2 * i]; t = e[2 * E + 2 * i]; }
    else     { s = e[i];     t = e[E + i]; }
}

// ---------------- CSR build ----------------

__global__ void count_kernel(const int* __restrict__ e, long long E,
                             const int* __restrict__ flag, int* __restrict__ cnt) {
    const bool i64 = (*flag != 0);
    long long i = (long long)blockIdx.x * blockDim.x + threadIdx.x;
    const long long stride = (long long)gridDim.x * blockDim.x;
    for (; i < E; i += stride) {
        int t = i64 ? e[2 * E + 2 * i] : e[E + i];
        atomicAdd(cnt + t, 1);
    }
}

__global__ void scan1_kernel(const int* __restrict__ cnt, int N, int* __restrict__ bsum) {
    __shared__ int sh[SCAN_TPB];
    int base = blockIdx.x * SCAN_ELEMS + threadIdx.x * 16;
    int s = 0;
#pragma unroll
    for (int k = 0; k < 16; ++k) {
        int idx = base + k;
        if (idx < N) s += cnt[idx];
    }
    sh[threadIdx.x] = s;
    __syncthreads();
    for (int off = SCAN_TPB >> 1; off > 0; off >>= 1) {
        if (threadIdx.x < off) sh[threadIdx.x] += sh[threadIdx.x + off];
        __syncthreads();
    }
    if (threadIdx.x == 0) bsum[blockIdx.x] = sh[0];
}

__global__ void scan2_kernel(int* __restrict__ bsum, int nb) {
    if (blockIdx.x == 0 && threadIdx.x == 0) {
        int run = 0;
        for (int b = 0; b < nb; ++b) { int t = bsum[b]; bsum[b] = run; run += t; }
    }
}

__global__ void scan3_kernel(const int* __restrict__ cnt, int N, long long E,
                             const int* __restrict__ bsum,
                             int* __restrict__ row_ptr, int* __restrict__ cursor) {
    __shared__ int sh[SCAN_TPB];
    int base = blockIdx.x * SCAN_ELEMS + threadIdx.x * 16;
    int vals[16];
    int mySum = 0;
#pragma unroll
    for (int k = 0; k < 16; ++k) {
        int idx = base + k;
        vals[k] = (idx < N) ? cnt[idx] : 0;
        mySum += vals[k];
    }
    sh[threadIdx.x] = mySum;
    __syncthreads();
    // inclusive Hillis-Steele
    for (int off = 1; off < SCAN_TPB; off <<= 1) {
        int v = (threadIdx.x >= off) ? sh[threadIdx.x - off] : 0;
        __syncthreads();
        sh[threadIdx.x] += v;
        __syncthreads();
    }
    int run = bsum[blockIdx.x] + sh[threadIdx.x] - mySum;  // exclusive
#pragma unroll
    for (int k = 0; k < 16; ++k) {
        int idx = base + k;
        if (idx < N) { row_ptr[idx] = run; cursor[idx] = run; run += vals[k]; }
    }
    if (blockIdx.x == 0 && threadIdx.x == 0) row_ptr[N] = (int)E;
}

__global__ void fill_kernel(const int* __restrict__ e, long long E,
                            const int* __restrict__ flag,
                            int* __restrict__ cursor, int* __restrict__ csr) {
    const bool i64 = (*flag != 0);
    long long i = (long long)blockIdx.x * blockDim.x + threadIdx.x;
    const long long stride = (long long)gridDim.x * blockDim.x;
    for (; i < E; i += stride) {
        int s, t;
        edge_sd(e, E, i64, i, s, t);
        int pos = atomicAdd(cursor + t, 1);
        csr[pos] = s;
    }
}

// ---------------- fused layers (CSR path) ----------------

// dinv from row_ptr; p = x * dinv
__global__ void node_init_csr_kernel(const float* __restrict__ x,
                                     const int* __restrict__ row_ptr,
                                     float* __restrict__ dinv, float* __restrict__ p, int N) {
    int i = blockIdx.x * blockDim.x + threadIdx.x;
    if (i >= N) return;
    int c = row_ptr[i + 1] - row_ptr[i];
    float di = rsqrtf((float)c + 1.0f);
    dinv[i] = di;
    p[i] = x[i] * di;
}

// layer1: scalar gather of p; h1 = relu(dinv*(sum+p)*W1 + b1); y2 = dinv*(h1@W2)
__global__ void layer1_kernel(const int* __restrict__ row_ptr, const int* __restrict__ csr,
                              const float* __restrict__ p, const float* __restrict__ dinv,
                              const float* __restrict__ W1, const float* __restrict__ b1,
                              const float* __restrict__ W2,
                              float4* __restrict__ y2, int N) {
    int i = blockIdx.x * blockDim.x + threadIdx.x;
    if (i >= N) return;
    int beg = row_ptr[i], end = row_ptr[i + 1];
    float a = 0.0f;
    int k = beg;
    for (; k + 4 <= end; k += 4) {
        int s0 = csr[k], s1 = csr[k + 1], s2 = csr[k + 2], s3 = csr[k + 3];
        float v0 = p[s0], v1 = p[s1], v2 = p[s2], v3 = p[s3];
        a += (v0 + v1) + (v2 + v3);
    }
    for (; k < end; ++k) a += p[csr[k]];
    float di = dinv[i];
    float t = di * (a + p[i]);
    float h0 = fmaxf(t * W1[0] + b1[0], 0.0f);
    float h1 = fmaxf(t * W1[1] + b1[1], 0.0f);
    float h2 = fmaxf(t * W1[2] + b1[2], 0.0f);
    float4 o;
    o.x = di * (h0 * W2[0] + h1 * W2[3] + h2 * W2[6]);
    o.y = di * (h0 * W2[1] + h1 * W2[4] + h2 * W2[7]);
    o.z = di * (h0 * W2[2] + h1 * W2[5] + h2 * W2[8]);
    o.w = 0.0f;
    y2[i] = o;
}

// middle layer: float4 gathers; ynext = dinv*(relu(dinv*(sum+y[i])+b)@Wn)
__global__ void layer_mid_kernel(const int* __restrict__ row_ptr, const int* __restrict__ csr,
                                 const float4* __restrict__ y, const float* __restrict__ dinv,
                                 const float* __restrict__ b, const float* __restrict__ Wn,
                                 float4* __restrict__ ynext, int N) {
    int i = blockIdx.x * blockDim.x + threadIdx.x;
    if (i >= N) return;
    int beg = row_ptr[i], end = row_ptr[i + 1];
    float a0 = 0.0f, a1 = 0.0f, a2 = 0.0f;
    int k = beg;
    for (; k + 4 <= end; k += 4) {
        int s0 = csr[k], s1 = csr[k + 1], s2 = csr[k + 2], s3 = csr[k + 3];
        float4 v0 = y[s0], v1 = y[s1], v2 = y[s2], v3 = y[s3];
        a0 += (v0.x + v1.x) + (v2.x + v3.x);
        a1 += (v0.y + v1.y) + (v2.y + v3.y);
        a2 += (v0.z + v1.z) + (v2.z + v3.z);
    }
    for (; k < end; ++k) { float4 v = y[csr[k]]; a0 += v.x; a1 += v.y; a2 += v.z; }
    float di = dinv[i];
    float4 yi = y[i];
    float h0 = fmaxf(di * (a0 + yi.x) + b[0], 0.0f);
    float h1 = fmaxf(di * (a1 + yi.y) + b[1], 0.0f);
    float h2 = fmaxf(di * (a2 + yi.z) + b[2], 0.0f);
    float4 o;
    o.x = di * (h0 * Wn[0] + h1 * Wn[3] + h2 * Wn[6]);
    o.y = di * (h0 * Wn[1] + h1 * Wn[4] + h2 * Wn[7]);
    o.z = di * (h0 * Wn[2] + h1 * Wn[5] + h2 * Wn[8]);
    o.w = 0.0f;
    ynext[i] = o;
}

// last layer: out = relu(dinv*(sum+y[i])+b)
__global__ void layer_last_kernel(const int* __restrict__ row_ptr, const int* __restrict__ csr,
                                  const float4* __restrict__ y, const float* __restrict__ dinv,
                                  const float* __restrict__ b,
                                  float* __restrict__ out, int N) {
    int i = blockIdx.x * blockDim.x + threadIdx.x;
    if (i >= N) return;
    int beg = row_ptr[i], end = row_ptr[i + 1];
    float a0 = 0.0f, a1 = 0.0f, a2 = 0.0f;
    int k = beg;
    for (; k + 4 <= end; k += 4) {
        int s0 = csr[k], s1 = csr[k + 1], s2 = csr[k + 2], s3 = csr[k + 3];
        float4 v0 = y[s0], v1 = y[s1], v2 = y[s2], v3 = y[s3];
        a0 += (v0.x + v1.x) + (v2.x + v3.x);
        a1 += (v0.y + v1.y) + (v2.y + v3.y);
        a2 += (v0.z + v1.z) + (v2.z + v3.z);
    }
    for (; k < end; ++k) { float4 v = y[csr[k]]; a0 += v.x; a1 += v.y; a2 += v.z; }
    float di = dinv[i];
    float4 yi = y[i];
    out[i * 3 + 0] = fmaxf(di * (a0 + yi.x) + b[0], 0.0f);
    out[i * 3 + 1] = fmaxf(di * (a1 + yi.y) + b[1], 0.0f);
    out[i * 3 + 2] = fmaxf(di * (a2 + yi.z) + b[2], 0.0f);
}

// ---------------- fallback (atomic scatter path, known-good) ----------------

__global__ void deg_kernel(const int* __restrict__ e, long long E,
                           const int* __restrict__ flag, float* __restrict__ deg) {
    const bool i64 = (*flag != 0);
    long long i = (long long)blockIdx.x * blockDim.x + threadIdx.x;
    const long long stride = (long long)gridDim.x * blockDim.x;
    for (; i < E; i += stride) {
        long long t = i64 ? (long long)e[2 * E + 2 * i] : (long long)e[E + i];
        atomicAdd(deg + t, 1.0f);
    }
}

__global__ void node_init_kernel(const float* __restrict__ x, const float* __restrict__ W1,
                                 float* __restrict__ deg_dinv, float* __restrict__ A, int N) {
    int i = blockIdx.x * blockDim.x + threadIdx.x;
    if (i >= N) return;
    float di = rsqrtf(deg_dinv[i] + 1.0f);
    deg_dinv[i] = di;
    float v = x[i] * di;
    A[i * 3 + 0] = v * W1[0];
    A[i * 3 + 1] = v * W1[1];
    A[i * 3 + 2] = v * W1[2];
}

__global__ void scatter_kernel(const int* __restrict__ e, long long E,
                               const int* __restrict__ flag,
                               const float* __restrict__ y, float* __restrict__ acc) {
    const bool i64 = (*flag != 0);
    long long i = (long long)blockIdx.x * blockDim.x + threadIdx.x;
    const long long stride = (long long)gridDim.x * blockDim.x;
    for (; i < E; i += stride) {
        int s, t;
        edge_sd(e, E, i64, i, s, t);
        atomicAdd(acc + (long long)t * 3 + 0, y[(long long)s * 3 + 0]);
        atomicAdd(acc + (long long)t * 3 + 1, y[(long long)s * 3 + 1]);
        atomicAdd(acc + (long long)t * 3 + 2, y[(long long)s * 3 + 2]);
    }
}

__global__ void finalize_mid_kernel(const float* __restrict__ dinv, const float* __restrict__ y,
                                    float* __restrict__ acc, const float* __restrict__ b,
                                    const float* __restrict__ Wn, int N) {
    int i = blockIdx.x * blockDim.x + threadIdx.x;
    if (i >= N) return;
    float di = dinv[i];
    float h0 = fmaxf(di * (acc[i * 3 + 0] + y[i * 3 + 0]) + b[0], 0.0f);
    float h1 = fmaxf(di * (acc[i * 3 + 1] + y[i * 3 + 1]) + b[1], 0.0f);
    float h2 = fmaxf(di * (acc[i * 3 + 2] + y[i * 3 + 2]) + b[2], 0.0f);
    float z0 = di * (h0 * Wn[0] + h1 * Wn[3] + h2 * Wn[6]);
    float z1 = di * (h0 * Wn[1] + h1 * Wn[4] + h2 * Wn[7]);
    float z2 = di * (h0 * Wn[2] + h1 * Wn[5] + h2 * Wn[8]);
    acc[i * 3 + 0] = z0;
    acc[i * 3 + 1] = z1;
    acc[i * 3 + 2] = z2;
}

__global__ void finalize_last_kernel(const float* __restrict__ dinv, const float* __restrict__ y,
                                     const float* __restrict__ acc, const float* __restrict__ b,
                                     float* __restrict__ out, int N) {
    int i = blockIdx.x * blockDim.x + threadIdx.x;
    if (i >= N) return;
    float di = dinv[i];
    out[i * 3 + 0] = fmaxf(di * (acc[i * 3 + 0] + y[i * 3 + 0]) + b[0], 0.0f);
    out[i * 3 + 1] = fmaxf(di * (acc[i * 3 + 1] + y[i * 3 + 1]) + b[1], 0.0f);
    out[i * 3 + 2] = fmaxf(di * (acc[i * 3 + 2] + y[i * 3 + 2]) + b[2], 0.0f);
}

// ---------------- launch ----------------

extern "C" void kernel_launch(void* const* d_in, const int* in_sizes, int n_in,
                              void* d_out, int out_size, void* d_ws, size_t ws_size,
                              hipStream_t stream) {
    const float* x  = (const float*)d_in[0];
    const int*   ei = (const int*)d_in[1];
    const float* W1 = (const float*)d_in[2];
    const float* b1 = (const float*)d_in[3];
    const float* W2 = (const float*)d_in[4];
    const float* b2 = (const float*)d_in[5];
    const float* W3 = (const float*)d_in[6];
    const float* b3 = (const float*)d_in[7];
    float* out = (float*)d_out;

    const long long N = in_sizes[0];
    const long long E = (long long)in_sizes[1] / 2;

    char* w = (char*)d_ws;
    size_t off = 0;
    auto alloc = [&](size_t bytes) -> char* {
        char* pp = w + off;
        off = (off + bytes + 255) & ~(size_t)255;
        return pp;
    };

    int*   flag    = (int*)alloc(4);
    int*   cnt     = (int*)alloc((size_t)N * 4);
    int*   row_ptr = (int*)alloc(((size_t)N + 1) * 4);
    int*   cursor  = (int*)alloc((size_t)N * 4);
    int*   csr     = (int*)alloc((size_t)E * 4);
    float* dinv    = (float*)alloc((size_t)N * 4);
    float* p       = (float*)alloc((size_t)N * 4);
    float4* y2     = (float4*)alloc((size_t)N * 16);
    float4* y3     = (float4*)alloc((size_t)N * 16);

    const int nblk = (int)((N + THREADS - 1) / THREADS);
    const int eblk = 2048;
    const int nb_scan = (int)((N + SCAN_ELEMS - 1) / SCAN_ELEMS);

    if (off <= ws_size) {
        // ---- CSR path ----
        detect_i64_kernel<<<1, 64, 0, stream>>>(ei, flag);
        hipMemsetAsync(cnt, 0, (size_t)N * 4, stream);
        count_kernel<<<eblk, THREADS, 0, stream>>>(ei, E, flag, cnt);
        // reuse dinv's space for block sums during scan (overwritten later)
        int* bsum = (int*)p;  // p not yet live; nb_scan ints << N
        scan1_kernel<<<nb_scan, SCAN_TPB, 0, stream>>>(cnt, (int)N, bsum);
        scan2_kernel<<<1, 64, 0, stream>>>(bsum, nb_scan);
        scan3_kernel<<<nb_scan, SCAN_TPB, 0, stream>>>(cnt, (int)N, E, bsum, row_ptr, cursor);
        fill_kernel<<<eblk, THREADS, 0, stream>>>(ei, E, flag, cursor, csr);

        node_init_csr_kernel<<<nblk, THREADS, 0, stream>>>(x, row_ptr, dinv, p, (int)N);
        layer1_kernel<<<nblk, THREADS, 0, stream>>>(row_ptr, csr, p, dinv, W1, b1, W2, y2, (int)N);
        layer_mid_kernel<<<nblk, THREADS, 0, stream>>>(row_ptr, csr, y2, dinv, b2, W3, y3, (int)N);
        layer_last_kernel<<<nblk, THREADS, 0, stream>>>(row_ptr, csr, y3, dinv, b3, out, (int)N);
    } else {
        // ---- fallback: atomic scatter path ----
        int*   fflag = (int*)w;
        float* fdinv = (float*)(w + 256);
        float* A     = fdinv + N;
        size_t need_full = 256 + (size_t)N * 4 + (size_t)N * 12 * 2;
        float* B = (ws_size >= need_full) ? (A + 3 * N) : out;

        detect_i64_kernel<<<1, 64, 0, stream>>>(ei, fflag);
        hipMemsetAsync(fdinv, 0, (size_t)N * 4, stream);
        deg_kernel<<<eblk, THREADS, 0, stream>>>(ei, E, fflag, fdinv);
        node_init_kernel<<<nblk, THREADS, 0, stream>>>(x, W1, fdinv, A, (int)N);

        hipMemsetAsync(B, 0, (size_t)N * 12, stream);
        scatter_kernel<<<eblk, THREADS, 0, stream>>>(ei, E, fflag, A, B);
        finalize_mid_kernel<<<nblk, THREADS, 0, stream>>>(fdinv, A, B, b1, W2, (int)N);

        hipMemsetAsync(A, 0, (size_t)N * 12, stream);
        scatter_kernel<<<eblk, THREADS, 0, stream>>>(ei, E, fflag, B, A);
        finalize_mid_kernel<<<nblk, THREADS, 0, stream>>>(fdinv, B, A, b2, W3, (int)N);

        hipMemsetAsync(B, 0, (size_t)N * 12, stream);
        scatter_kernel<<<eblk, THREADS, 0, stream>>>(ei, E, fflag, A, B);
        finalize_last_kernel<<<nblk, THREADS, 0, stream>>>(fdinv, A, B, b3, out, (int)N);
    }
}

// Round 3
// 894.248 us; speedup vs baseline: 8.7580x; 2.5268x over previous
//
#include <hip/hip_runtime.h>

#define THREADS 256
#define SCAN_TPB 256
#define SCAN_ELEMS 4096      // 16 per thread * 256
#define CHUNK 16384          // edges per block in hist/scatter
#define BUCKET_BITS 10
#define BUCKET_SIZE 1024
#define MAXBUCK 4096         // LDS table cap (supports N <= 4M; packing needs N <= 1M)

__device__ __forceinline__ long long llmin(long long a, long long b) { return a < b ? a : b; }

// ---------------- common ----------------

__global__ void detect_i64_kernel(const int* __restrict__ e, int* __restrict__ flag) {
    if (blockIdx.x == 0 && threadIdx.x == 0) {
        bool all_odd_zero = true, any_even = false;
#pragma unroll
        for (int k = 0; k < 16; ++k) {
            if (e[2 * k + 1] != 0) all_odd_zero = false;
            if (e[2 * k] != 0) any_even = true;
        }
        *flag = (all_odd_zero && any_even) ? 1 : 0;
    }
}

// ---------------- binned edge build (no global atomics) ----------------

// per-chunk histogram of dst buckets -> H[bucket * nchunks + chunk]
__global__ void hist_kernel(const int* __restrict__ e, long long E,
                            const int* __restrict__ flag,
                            int nchunks, int nbuck, int* __restrict__ H) {
    __shared__ int hist[MAXBUCK];
    for (int b = threadIdx.x; b < nbuck; b += blockDim.x) hist[b] = 0;
    __syncthreads();
    const bool i64 = (*flag != 0);
    long long beg = (long long)blockIdx.x * CHUNK;
    long long end = llmin(beg + CHUNK, E);
    if (i64) {
        const int2* d = (const int2*)e + E;   // dst int64 j at int2 index E + j
        for (long long i = beg + threadIdx.x; i < end; i += blockDim.x)
            atomicAdd(&hist[d[i].x >> BUCKET_BITS], 1);
    } else {
        const int* d = e + E;
        for (long long i = beg + threadIdx.x; i < end; i += blockDim.x)
            atomicAdd(&hist[d[i] >> BUCKET_BITS], 1);
    }
    __syncthreads();
    for (int b = threadIdx.x; b < nbuck; b += blockDim.x)
        H[(size_t)b * nchunks + blockIdx.x] = hist[b];
}

// 3-kernel exclusive scan over len elements, in place (H -> offsets)
__global__ void scan1_kernel(const int* __restrict__ v, int len, int* __restrict__ bsum) {
    __shared__ int sh[SCAN_TPB];
    int base = blockIdx.x * SCAN_ELEMS + threadIdx.x * 16;
    int s = 0;
#pragma unroll
    for (int k = 0; k < 16; ++k) {
        int idx = base + k;
        if (idx < len) s += v[idx];
    }
    sh[threadIdx.x] = s;
    __syncthreads();
    for (int off = SCAN_TPB >> 1; off > 0; off >>= 1) {
        if (threadIdx.x < off) sh[threadIdx.x] += sh[threadIdx.x + off];
        __syncthreads();
    }
    if (threadIdx.x == 0) bsum[blockIdx.x] = sh[0];
}

__global__ void scan2_kernel(int* __restrict__ bsum, int nb) {
    if (blockIdx.x == 0 && threadIdx.x == 0) {
        int run = 0;
        for (int b = 0; b < nb; ++b) { int t = bsum[b]; bsum[b] = run; run += t; }
    }
}

__global__ void scan3_kernel(int* __restrict__ v, int len, const int* __restrict__ bsum) {
    __shared__ int sh[SCAN_TPB];
    int base = blockIdx.x * SCAN_ELEMS + threadIdx.x * 16;
    int vals[16];
    int mySum = 0;
#pragma unroll
    for (int k = 0; k < 16; ++k) {
        int idx = base + k;
        vals[k] = (idx < len) ? v[idx] : 0;
        mySum += vals[k];
    }
    sh[threadIdx.x] = mySum;
    __syncthreads();
    for (int off = 1; off < SCAN_TPB; off <<= 1) {
        int t = (threadIdx.x >= off) ? sh[threadIdx.x - off] : 0;
        __syncthreads();
        sh[threadIdx.x] += t;
        __syncthreads();
    }
    int run = bsum[blockIdx.x] + sh[threadIdx.x] - mySum;  // exclusive
#pragma unroll
    for (int k = 0; k < 16; ++k) {
        int idx = base + k;
        if (idx < len) { v[idx] = run; run += vals[k]; }
    }
}

__global__ void bstart_kernel(const int* __restrict__ H, int nchunks, int nbuck,
                              long long E, int* __restrict__ bs) {
    int b = blockIdx.x * blockDim.x + threadIdx.x;
    if (b < nbuck) bs[b] = H[(size_t)b * nchunks];
    if (b == 0) bs[nbuck] = (int)E;
}

// re-read edges, write packed records ((dst&1023)<<20 | src) grouped by bucket
__global__ void scatter_pack_kernel(const int* __restrict__ e, long long E,
                                    const int* __restrict__ flag,
                                    int nchunks, int nbuck, const int* __restrict__ H,
                                    int* __restrict__ packed) {
    __shared__ int cur[MAXBUCK];
    for (int b = threadIdx.x; b < nbuck; b += blockDim.x)
        cur[b] = H[(size_t)b * nchunks + blockIdx.x];
    __syncthreads();
    const bool i64 = (*flag != 0);
    long long beg = (long long)blockIdx.x * CHUNK;
    long long end = llmin(beg + CHUNK, E);
    for (long long i = beg + threadIdx.x; i < end; i += blockDim.x) {
        int s, t;
        if (i64) { s = ((const int2*)e)[i].x; t = ((const int2*)e)[E + i].x; }
        else     { s = e[i];                  t = e[E + i]; }
        int b = t >> BUCKET_BITS;
        int pos = atomicAdd(&cur[b], 1);   // LDS atomic, returns old
        packed[pos] = ((t & (BUCKET_SIZE - 1)) << 20) | s;
    }
}

// ---------------- bucketed fused layers ----------------

// deg via LDS count; dinv = rsqrt(deg+1); p = x * dinv
__global__ void deg_init_kernel(const int* __restrict__ bs, const int* __restrict__ packed,
                                const float* __restrict__ x,
                                float* __restrict__ dinv, float* __restrict__ p, int N) {
    __shared__ int cnt[BUCKET_SIZE];
    for (int k = threadIdx.x; k < BUCKET_SIZE; k += blockDim.x) cnt[k] = 0;
    __syncthreads();
    int beg = bs[blockIdx.x], end = bs[blockIdx.x + 1];
    for (int k = beg + threadIdx.x; k < end; k += blockDim.x)
        atomicAdd(&cnt[((unsigned)packed[k]) >> 20], 1);
    __syncthreads();
    int base = blockIdx.x << BUCKET_BITS;
    for (int k = threadIdx.x; k < BUCKET_SIZE; k += blockDim.x) {
        int i = base + k;
        if (i < N) {
            float di = rsqrtf((float)cnt[k] + 1.0f);
            dinv[i] = di;
            p[i] = x[i] * di;
        }
    }
}

// layer1: scalar accumulate p[src] per dst; y2 = dinv*(relu(dinv*(a+p)*W1+b1)@W2)
__global__ void layer1_bucket_kernel(const int* __restrict__ bs, const int* __restrict__ packed,
                                     const float* __restrict__ p, const float* __restrict__ dinv,
                                     const float* __restrict__ W1, const float* __restrict__ b1,
                                     const float* __restrict__ W2,
                                     float4* __restrict__ y2, int N) {
    __shared__ float acc[BUCKET_SIZE];
    for (int k = threadIdx.x; k < BUCKET_SIZE; k += blockDim.x) acc[k] = 0.0f;
    __syncthreads();
    int beg = bs[blockIdx.x], end = bs[blockIdx.x + 1];
    for (int k = beg + threadIdx.x; k < end; k += blockDim.x) {
        unsigned rec = (unsigned)packed[k];
        atomicAdd(&acc[rec >> 20], p[rec & 0xFFFFFu]);
    }
    __syncthreads();
    int base = blockIdx.x << BUCKET_BITS;
    for (int k = threadIdx.x; k < BUCKET_SIZE; k += blockDim.x) {
        int i = base + k;
        if (i >= N) continue;
        float di = dinv[i];
        float t = di * (acc[k] + p[i]);
        float h0 = fmaxf(t * W1[0] + b1[0], 0.0f);
        float h1 = fmaxf(t * W1[1] + b1[1], 0.0f);
        float h2 = fmaxf(t * W1[2] + b1[2], 0.0f);
        float4 o;
        o.x = di * (h0 * W2[0] + h1 * W2[3] + h2 * W2[6]);
        o.y = di * (h0 * W2[1] + h1 * W2[4] + h2 * W2[7]);
        o.z = di * (h0 * W2[2] + h1 * W2[5] + h2 * W2[8]);
        o.w = 0.0f;
        y2[i] = o;
    }
}

// mid layer: float4 gather accumulate; ynext = dinv*(relu(dinv*(a+y)+b)@Wn)
__global__ void layer_mid_bucket_kernel(const int* __restrict__ bs, const int* __restrict__ packed,
                                        const float4* __restrict__ y, const float* __restrict__ dinv,
                                        const float* __restrict__ b, const float* __restrict__ Wn,
                                        float4* __restrict__ ynext, int N) {
    __shared__ float acc[BUCKET_SIZE * 3];
    for (int k = threadIdx.x; k < BUCKET_SIZE * 3; k += blockDim.x) acc[k] = 0.0f;
    __syncthreads();
    int beg = bs[blockIdx.x], end = bs[blockIdx.x + 1];
    for (int k = beg + threadIdx.x; k < end; k += blockDim.x) {
        unsigned rec = (unsigned)packed[k];
        float4 v = y[rec & 0xFFFFFu];
        int dl = (rec >> 20) * 3;
        atomicAdd(&acc[dl + 0], v.x);
        atomicAdd(&acc[dl + 1], v.y);
        atomicAdd(&acc[dl + 2], v.z);
    }
    __syncthreads();
    int base = blockIdx.x << BUCKET_BITS;
    for (int k = threadIdx.x; k < BUCKET_SIZE; k += blockDim.x) {
        int i = base + k;
        if (i >= N) continue;
        float di = dinv[i];
        float4 yi = y[i];
        float h0 = fmaxf(di * (acc[k * 3 + 0] + yi.x) + b[0], 0.0f);
        float h1 = fmaxf(di * (acc[k * 3 + 1] + yi.y) + b[1], 0.0f);
        float h2 = fmaxf(di * (acc[k * 3 + 2] + yi.z) + b[2], 0.0f);
        float4 o;
        o.x = di * (h0 * Wn[0] + h1 * Wn[3] + h2 * Wn[6]);
        o.y = di * (h0 * Wn[1] + h1 * Wn[4] + h2 * Wn[7]);
        o.z = di * (h0 * Wn[2] + h1 * Wn[5] + h2 * Wn[8]);
        o.w = 0.0f;
        ynext[i] = o;
    }
}

// last layer: out = relu(dinv*(a+y)+b)
__global__ void layer_last_bucket_kernel(const int* __restrict__ bs, const int* __restrict__ packed,
                                         const float4* __restrict__ y, const float* __restrict__ dinv,
                                         const float* __restrict__ b,
                                         float* __restrict__ out, int N) {
    __shared__ float acc[BUCKET_SIZE * 3];
    for (int k = threadIdx.x; k < BUCKET_SIZE * 3; k += blockDim.x) acc[k] = 0.0f;
    __syncthreads();
    int beg = bs[blockIdx.x], end = bs[blockIdx.x + 1];
    for (int k = beg + threadIdx.x; k < end; k += blockDim.x) {
        unsigned rec = (unsigned)packed[k];
        float4 v = y[rec & 0xFFFFFu];
        int dl = (rec >> 20) * 3;
        atomicAdd(&acc[dl + 0], v.x);
        atomicAdd(&acc[dl + 1], v.y);
        atomicAdd(&acc[dl + 2], v.z);
    }
    __syncthreads();
    int base = blockIdx.x << BUCKET_BITS;
    for (int k = threadIdx.x; k < BUCKET_SIZE; k += blockDim.x) {
        int i = base + k;
        if (i >= N) continue;
        float di = dinv[i];
        float4 yi = y[i];
        out[i * 3 + 0] = fmaxf(di * (acc[k * 3 + 0] + yi.x) + b[0], 0.0f);
        out[i * 3 + 1] = fmaxf(di * (acc[k * 3 + 1] + yi.y) + b[1], 0.0f);
        out[i * 3 + 2] = fmaxf(di * (acc[k * 3 + 2] + yi.z) + b[2], 0.0f);
    }
}

// ---------------- fallback (atomic scatter path, known-good R0) ----------------

__global__ void deg_kernel(const int* __restrict__ e, long long E,
                           const int* __restrict__ flag, float* __restrict__ deg) {
    const bool i64 = (*flag != 0);
    long long i = (long long)blockIdx.x * blockDim.x + threadIdx.x;
    const long long stride = (long long)gridDim.x * blockDim.x;
    for (; i < E; i += stride) {
        long long t = i64 ? (long long)e[2 * E + 2 * i] : (long long)e[E + i];
        atomicAdd(deg + t, 1.0f);
    }
}

__global__ void node_init_kernel(const float* __restrict__ x, const float* __restrict__ W1,
                                 float* __restrict__ deg_dinv, float* __restrict__ A, int N) {
    int i = blockIdx.x * blockDim.x + threadIdx.x;
    if (i >= N) return;
    float di = rsqrtf(deg_dinv[i] + 1.0f);
    deg_dinv[i] = di;
    float v = x[i] * di;
    A[i * 3 + 0] = v * W1[0];
    A[i * 3 + 1] = v * W1[1];
    A[i * 3 + 2] = v * W1[2];
}

__global__ void scatter_kernel(const int* __restrict__ e, long long E,
                               const int* __restrict__ flag,
                               const float* __restrict__ y, float* __restrict__ acc) {
    const bool i64 = (*flag != 0);
    long long i = (long long)blockIdx.x * blockDim.x + threadIdx.x;
    const long long stride = (long long)gridDim.x * blockDim.x;
    for (; i < E; i += stride) {
        int s, t;
        if (i64) { s = e[2 * i]; t = e[2 * E + 2 * i]; }
        else     { s = e[i];     t = e[E + i]; }
        atomicAdd(acc + (long long)t * 3 + 0, y[(long long)s * 3 + 0]);
        atomicAdd(acc + (long long)t * 3 + 1, y[(long long)s * 3 + 1]);
        atomicAdd(acc + (long long)t * 3 + 2, y[(long long)s * 3 + 2]);
    }
}

__global__ void finalize_mid_kernel(const float* __restrict__ dinv, const float* __restrict__ y,
                                    float* __restrict__ acc, const float* __restrict__ b,
                                    const float* __restrict__ Wn, int N) {
    int i = blockIdx.x * blockDim.x + threadIdx.x;
    if (i >= N) return;
    float di = dinv[i];
    float h0 = fmaxf(di * (acc[i * 3 + 0] + y[i * 3 + 0]) + b[0], 0.0f);
    float h1 = fmaxf(di * (acc[i * 3 + 1] + y[i * 3 + 1]) + b[1], 0.0f);
    float h2 = fmaxf(di * (acc[i * 3 + 2] + y[i * 3 + 2]) + b[2], 0.0f);
    float z0 = di * (h0 * Wn[0] + h1 * Wn[3] + h2 * Wn[6]);
    float z1 = di * (h0 * Wn[1] + h1 * Wn[4] + h2 * Wn[7]);
    float z2 = di * (h0 * Wn[2] + h1 * Wn[5] + h2 * Wn[8]);
    acc[i * 3 + 0] = z0;
    acc[i * 3 + 1] = z1;
    acc[i * 3 + 2] = z2;
}

__global__ void finalize_last_kernel(const float* __restrict__ dinv, const float* __restrict__ y,
                                     const float* __restrict__ acc, const float* __restrict__ b,
                                     float* __restrict__ out, int N) {
    int i = blockIdx.x * blockDim.x + threadIdx.x;
    if (i >= N) return;
    float di = dinv[i];
    out[i * 3 + 0] = fmaxf(di * (acc[i * 3 + 0] + y[i * 3 + 0]) + b[0], 0.0f);
    out[i * 3 + 1] = fmaxf(di * (acc[i * 3 + 1] + y[i * 3 + 1]) + b[1], 0.0f);
    out[i * 3 + 2] = fmaxf(di * (acc[i * 3 + 2] + y[i * 3 + 2]) + b[2], 0.0f);
}

// ---------------- launch ----------------

extern "C" void kernel_launch(void* const* d_in, const int* in_sizes, int n_in,
                              void* d_out, int out_size, void* d_ws, size_t ws_size,
                              hipStream_t stream) {
    const float* x  = (const float*)d_in[0];
    const int*   ei = (const int*)d_in[1];
    const float* W1 = (const float*)d_in[2];
    const float* b1 = (const float*)d_in[3];
    const float* W2 = (const float*)d_in[4];
    const float* b2 = (const float*)d_in[5];
    const float* W3 = (const float*)d_in[6];
    const float* b3 = (const float*)d_in[7];
    float* out = (float*)d_out;

    const long long N = in_sizes[0];
    const long long E = (long long)in_sizes[1] / 2;

    const int nbuck   = (int)((N + BUCKET_SIZE - 1) >> BUCKET_BITS);
    const int nchunks = (int)((E + CHUNK - 1) / CHUNK);
    const int len     = nbuck * nchunks;

    char* w = (char*)d_ws;
    size_t off = 0;
    auto alloc = [&](size_t bytes) -> char* {
        char* pp = w + off;
        off = (off + bytes + 255) & ~(size_t)255;
        return pp;
    };

    int*    flag   = (int*)alloc(4);
    int*    H      = (int*)alloc((size_t)len * 4);
    int*    bs     = (int*)alloc(((size_t)nbuck + 1) * 4);
    int*    packed = (int*)alloc((size_t)E * 4);
    float*  dinv   = (float*)alloc((size_t)N * 4);
    float*  p      = (float*)alloc((size_t)N * 4);
    float4* y2     = (float4*)alloc((size_t)N * 16);
    float4* y3     = (float4*)alloc((size_t)N * 16);

    const int nblk    = (int)((N + THREADS - 1) / THREADS);
    const int nb_scan = (len + SCAN_ELEMS - 1) / SCAN_ELEMS;

    if (off <= ws_size && N <= (1 << 20) && nbuck <= MAXBUCK) {
        detect_i64_kernel<<<1, 64, 0, stream>>>(ei, flag);
        hist_kernel<<<nchunks, THREADS, 0, stream>>>(ei, E, flag, nchunks, nbuck, H);
        int* bsum = (int*)p;  // p not yet live; nb_scan ints << N floats
        scan1_kernel<<<nb_scan, SCAN_TPB, 0, stream>>>(H, len, bsum);
        scan2_kernel<<<1, 64, 0, stream>>>(bsum, nb_scan);
        scan3_kernel<<<nb_scan, SCAN_TPB, 0, stream>>>(H, len, bsum);
        bstart_kernel<<<(nbuck + THREADS) / THREADS, THREADS, 0, stream>>>(H, nchunks, nbuck, E, bs);
        scatter_pack_kernel<<<nchunks, THREADS, 0, stream>>>(ei, E, flag, nchunks, nbuck, H, packed);

        deg_init_kernel<<<nbuck, THREADS, 0, stream>>>(bs, packed, x, dinv, p, (int)N);
        layer1_bucket_kernel<<<nbuck, THREADS, 0, stream>>>(bs, packed, p, dinv, W1, b1, W2, y2, (int)N);
        layer_mid_bucket_kernel<<<nbuck, THREADS, 0, stream>>>(bs, packed, y2, dinv, b2, W3, y3, (int)N);
        layer_last_bucket_kernel<<<nbuck, THREADS, 0, stream>>>(bs, packed, y3, dinv, b3, out, (int)N);
    } else {
        // ---- fallback: atomic scatter path (proven R0) ----
        int*   fflag = (int*)w;
        float* fdinv = (float*)(w + 256);
        float* A     = fdinv + N;
        size_t need_full = 256 + (size_t)N * 4 + (size_t)N * 12 * 2;
        float* B = (ws_size >= need_full) ? (A + 3 * N) : out;
        const int eblk = 2048;

        detect_i64_kernel<<<1, 64, 0, stream>>>(ei, fflag);
        hipMemsetAsync(fdinv, 0, (size_t)N * 4, stream);
        deg_kernel<<<eblk, THREADS, 0, stream>>>(ei, E, fflag, fdinv);
        node_init_kernel<<<nblk, THREADS, 0, stream>>>(x, W1, fdinv, A, (int)N);

        hipMemsetAsync(B, 0, (size_t)N * 12, stream);
        scatter_kernel<<<eblk, THREADS, 0, stream>>>(ei, E, fflag, A, B);
        finalize_mid_kernel<<<nblk, THREADS, 0, stream>>>(fdinv, A, B, b1, W2, (int)N);

        hipMemsetAsync(A, 0, (size_t)N * 12, stream);
        scatter_kernel<<<eblk, THREADS, 0, stream>>>(ei, E, fflag, B, A);
        finalize_mid_kernel<<<nblk, THREADS, 0, stream>>>(fdinv, B, A, b2, W3, (int)N);

        hipMemsetAsync(B, 0, (size_t)N * 12, stream);
        scatter_kernel<<<eblk, THREADS, 0, stream>>>(ei, E, fflag, A, B);
        finalize_last_kernel<<<nblk, THREADS, 0, stream>>>(fdinv, A, B, b3, out, (int)N);
    }
}

// Round 4
// 804.794 us; speedup vs baseline: 9.7315x; 1.1112x over previous
//
#include <hip/hip_runtime.h>

#define THREADS 256
#define TPB_E 512
#define SCAN_TPB 256
#define SCAN_ELEMS 4096      // 16 per thread * 256
#define SUBCHUNK 32768       // edges per hist block
#define GROUP 2              // sub-chunks per scatter block
#define BUCKET_BITS 10
#define BUCKET_SIZE 1024
#define MAXBUCK 4096

__device__ __forceinline__ long long llmin(long long a, long long b) { return a < b ? a : b; }

// ---------------- common ----------------

__global__ void detect_i64_kernel(const int* __restrict__ e, int* __restrict__ flag) {
    if (blockIdx.x == 0 && threadIdx.x == 0) {
        bool all_odd_zero = true, any_even = false;
#pragma unroll
        for (int k = 0; k < 16; ++k) {
            if (e[2 * k + 1] != 0) all_odd_zero = false;
            if (e[2 * k] != 0) any_even = true;
        }
        *flag = (all_odd_zero && any_even) ? 1 : 0;
    }
}

// ---------------- binned edge build (no global atomics) ----------------

// per-subchunk histogram of dst buckets -> H[bucket * nsub + sub]
__global__ void hist_kernel(const int* __restrict__ e, long long E,
                            const int* __restrict__ flag,
                            int nsub, int nbuck, int* __restrict__ H) {
    __shared__ int hist[MAXBUCK];
    for (int b = threadIdx.x; b < nbuck; b += blockDim.x) hist[b] = 0;
    __syncthreads();
    const bool i64 = (*flag != 0);
    long long beg = (long long)blockIdx.x * SUBCHUNK;
    long long end = llmin(beg + SUBCHUNK, E);
    if (i64) {
        const int2* d = (const int2*)e + E;
        for (long long i = beg + threadIdx.x; i < end; i += blockDim.x)
            atomicAdd(&hist[d[i].x >> BUCKET_BITS], 1);
    } else {
        const int* d = e + E;
        for (long long i = beg + threadIdx.x; i < end; i += blockDim.x)
            atomicAdd(&hist[d[i] >> BUCKET_BITS], 1);
    }
    __syncthreads();
    for (int b = threadIdx.x; b < nbuck; b += blockDim.x)
        H[(size_t)b * nsub + blockIdx.x] = hist[b];
}

// 3-kernel exclusive scan over len elements, in place
__global__ void scan1_kernel(const int* __restrict__ v, int len, int* __restrict__ bsum) {
    __shared__ int sh[SCAN_TPB];
    int base = blockIdx.x * SCAN_ELEMS + threadIdx.x * 16;
    int s = 0;
#pragma unroll
    for (int k = 0; k < 16; ++k) {
        int idx = base + k;
        if (idx < len) s += v[idx];
    }
    sh[threadIdx.x] = s;
    __syncthreads();
    for (int off = SCAN_TPB >> 1; off > 0; off >>= 1) {
        if (threadIdx.x < off) sh[threadIdx.x] += sh[threadIdx.x + off];
        __syncthreads();
    }
    if (threadIdx.x == 0) bsum[blockIdx.x] = sh[0];
}

__global__ void scan2_kernel(int* __restrict__ bsum, int nb) {
    if (blockIdx.x == 0 && threadIdx.x == 0) {
        int run = 0;
        for (int b = 0; b < nb; ++b) { int t = bsum[b]; bsum[b] = run; run += t; }
    }
}

__global__ void scan3_kernel(int* __restrict__ v, int len, const int* __restrict__ bsum) {
    __shared__ int sh[SCAN_TPB];
    int base = blockIdx.x * SCAN_ELEMS + threadIdx.x * 16;
    int vals[16];
    int mySum = 0;
#pragma unroll
    for (int k = 0; k < 16; ++k) {
        int idx = base + k;
        vals[k] = (idx < len) ? v[idx] : 0;
        mySum += vals[k];
    }
    sh[threadIdx.x] = mySum;
    __syncthreads();
    for (int off = 1; off < SCAN_TPB; off <<= 1) {
        int t = (threadIdx.x >= off) ? sh[threadIdx.x - off] : 0;
        __syncthreads();
        sh[threadIdx.x] += t;
        __syncthreads();
    }
    int run = bsum[blockIdx.x] + sh[threadIdx.x] - mySum;  // exclusive
#pragma unroll
    for (int k = 0; k < 16; ++k) {
        int idx = base + k;
        if (idx < len) { v[idx] = run; run += vals[k]; }
    }
}

__global__ void bstart_kernel(const int* __restrict__ H, int nsub, int nbuck,
                              long long E, int* __restrict__ bs) {
    int b = blockIdx.x * blockDim.x + threadIdx.x;
    if (b < nbuck) bs[b] = H[(size_t)b * nsub];
    if (b == 0) bs[nbuck] = (int)E;
}

// each block owns GROUP consecutive sub-chunks; one cursor per bucket starting
// at H[b][c0] — the union of the GROUP segments is contiguous, and record order
// within a bucket is irrelevant (sum aggregation), so a single running cursor
// over the union is correct and yields long (~536B) sequential write segments.
__global__ void scatter_pack_kernel(const int* __restrict__ e, long long E,
                                    const int* __restrict__ flag,
                                    int nsub, int nbuck, const int* __restrict__ H,
                                    int* __restrict__ packed) {
    __shared__ int cur[MAXBUCK];
    int c0 = blockIdx.x * GROUP;
    for (int b = threadIdx.x; b < nbuck; b += blockDim.x)
        cur[b] = H[(size_t)b * nsub + c0];
    __syncthreads();
    const bool i64 = (*flag != 0);
    long long beg = (long long)c0 * SUBCHUNK;
    long long end = llmin(beg + (long long)GROUP * SUBCHUNK, E);
    for (long long i = beg + threadIdx.x; i < end; i += blockDim.x) {
        int s, t;
        if (i64) { s = ((const int2*)e)[i].x; t = ((const int2*)e)[E + i].x; }
        else     { s = e[i];                  t = e[E + i]; }
        int b = t >> BUCKET_BITS;
        int pos = atomicAdd(&cur[b], 1);   // LDS atomic
        packed[pos] = ((t & (BUCKET_SIZE - 1)) << 20) | s;
    }
}

// ---------------- bucketed fused layers ----------------

__global__ void deg_init_kernel(const int* __restrict__ bs, const int* __restrict__ packed,
                                const float* __restrict__ x,
                                float* __restrict__ dinv, float* __restrict__ p, int N) {
    __shared__ int cnt[BUCKET_SIZE];
    for (int k = threadIdx.x; k < BUCKET_SIZE; k += blockDim.x) cnt[k] = 0;
    __syncthreads();
    int beg = bs[blockIdx.x], end = bs[blockIdx.x + 1];
    int stride = blockDim.x;
    int k = beg + threadIdx.x;
    for (; k + 3 * stride < end; k += 4 * stride) {
        unsigned r0 = packed[k], r1 = packed[k + stride];
        unsigned r2 = packed[k + 2 * stride], r3 = packed[k + 3 * stride];
        atomicAdd(&cnt[r0 >> 20], 1);
        atomicAdd(&cnt[r1 >> 20], 1);
        atomicAdd(&cnt[r2 >> 20], 1);
        atomicAdd(&cnt[r3 >> 20], 1);
    }
    for (; k < end; k += stride) atomicAdd(&cnt[((unsigned)packed[k]) >> 20], 1);
    __syncthreads();
    int base = blockIdx.x << BUCKET_BITS;
    for (int j = threadIdx.x; j < BUCKET_SIZE; j += blockDim.x) {
        int i = base + j;
        if (i < N) {
            float di = rsqrtf((float)cnt[j] + 1.0f);
            dinv[i] = di;
            p[i] = x[i] * di;
        }
    }
}

__global__ void layer1_bucket_kernel(const int* __restrict__ bs, const int* __restrict__ packed,
                                     const float* __restrict__ p, const float* __restrict__ dinv,
                                     const float* __restrict__ W1, const float* __restrict__ b1,
                                     const float* __restrict__ W2,
                                     float4* __restrict__ y2, int N) {
    __shared__ float acc[BUCKET_SIZE];
    for (int k = threadIdx.x; k < BUCKET_SIZE; k += blockDim.x) acc[k] = 0.0f;
    __syncthreads();
    int beg = bs[blockIdx.x], end = bs[blockIdx.x + 1];
    int stride = blockDim.x;
    int k = beg + threadIdx.x;
    for (; k + 3 * stride < end; k += 4 * stride) {
        unsigned r0 = packed[k], r1 = packed[k + stride];
        unsigned r2 = packed[k + 2 * stride], r3 = packed[k + 3 * stride];
        float v0 = p[r0 & 0xFFFFFu], v1 = p[r1 & 0xFFFFFu];
        float v2 = p[r2 & 0xFFFFFu], v3 = p[r3 & 0xFFFFFu];
        atomicAdd(&acc[r0 >> 20], v0);
        atomicAdd(&acc[r1 >> 20], v1);
        atomicAdd(&acc[r2 >> 20], v2);
        atomicAdd(&acc[r3 >> 20], v3);
    }
    for (; k < end; k += stride) {
        unsigned rec = (unsigned)packed[k];
        atomicAdd(&acc[rec >> 20], p[rec & 0xFFFFFu]);
    }
    __syncthreads();
    int base = blockIdx.x << BUCKET_BITS;
    for (int j = threadIdx.x; j < BUCKET_SIZE; j += blockDim.x) {
        int i = base + j;
        if (i >= N) continue;
        float di = dinv[i];
        float t = di * (acc[j] + p[i]);
        float h0 = fmaxf(t * W1[0] + b1[0], 0.0f);
        float h1 = fmaxf(t * W1[1] + b1[1], 0.0f);
        float h2 = fmaxf(t * W1[2] + b1[2], 0.0f);
        float4 o;
        o.x = di * (h0 * W2[0] + h1 * W2[3] + h2 * W2[6]);
        o.y = di * (h0 * W2[1] + h1 * W2[4] + h2 * W2[7]);
        o.z = di * (h0 * W2[2] + h1 * W2[5] + h2 * W2[8]);
        o.w = 0.0f;
        y2[i] = o;
    }
}

__global__ void layer_mid_bucket_kernel(const int* __restrict__ bs, const int* __restrict__ packed,
                                        const float4* __restrict__ y, const float* __restrict__ dinv,
                                        const float* __restrict__ b, const float* __restrict__ Wn,
                                        float4* __restrict__ ynext, int N) {
    __shared__ float acc[BUCKET_SIZE * 3];
    for (int k = threadIdx.x; k < BUCKET_SIZE * 3; k += blockDim.x) acc[k] = 0.0f;
    __syncthreads();
    int beg = bs[blockIdx.x], end = bs[blockIdx.x + 1];
    int stride = blockDim.x;
    int k = beg + threadIdx.x;
    for (; k + 3 * stride < end; k += 4 * stride) {
        unsigned r0 = packed[k], r1 = packed[k + stride];
        unsigned r2 = packed[k + 2 * stride], r3 = packed[k + 3 * stride];
        float4 v0 = y[r0 & 0xFFFFFu], v1 = y[r1 & 0xFFFFFu];
        float4 v2 = y[r2 & 0xFFFFFu], v3 = y[r3 & 0xFFFFFu];
        int d0 = (r0 >> 20) * 3, d1 = (r1 >> 20) * 3, d2 = (r2 >> 20) * 3, d3 = (r3 >> 20) * 3;
        atomicAdd(&acc[d0 + 0], v0.x); atomicAdd(&acc[d0 + 1], v0.y); atomicAdd(&acc[d0 + 2], v0.z);
        atomicAdd(&acc[d1 + 0], v1.x); atomicAdd(&acc[d1 + 1], v1.y); atomicAdd(&acc[d1 + 2], v1.z);
        atomicAdd(&acc[d2 + 0], v2.x); atomicAdd(&acc[d2 + 1], v2.y); atomicAdd(&acc[d2 + 2], v2.z);
        atomicAdd(&acc[d3 + 0], v3.x); atomicAdd(&acc[d3 + 1], v3.y); atomicAdd(&acc[d3 + 2], v3.z);
    }
    for (; k < end; k += stride) {
        unsigned rec = (unsigned)packed[k];
        float4 v = y[rec & 0xFFFFFu];
        int dl = (rec >> 20) * 3;
        atomicAdd(&acc[dl + 0], v.x);
        atomicAdd(&acc[dl + 1], v.y);
        atomicAdd(&acc[dl + 2], v.z);
    }
    __syncthreads();
    int base = blockIdx.x << BUCKET_BITS;
    for (int j = threadIdx.x; j < BUCKET_SIZE; j += blockDim.x) {
        int i = base + j;
        if (i >= N) continue;
        float di = dinv[i];
        float4 yi = y[i];
        float h0 = fmaxf(di * (acc[j * 3 + 0] + yi.x) + b[0], 0.0f);
        float h1 = fmaxf(di * (acc[j * 3 + 1] + yi.y) + b[1], 0.0f);
        float h2 = fmaxf(di * (acc[j * 3 + 2] + yi.z) + b[2], 0.0f);
        float4 o;
        o.x = di * (h0 * Wn[0] + h1 * Wn[3] + h2 * Wn[6]);
        o.y = di * (h0 * Wn[1] + h1 * Wn[4] + h2 * Wn[7]);
        o.z = di * (h0 * Wn[2] + h1 * Wn[5] + h2 * Wn[8]);
        o.w = 0.0f;
        ynext[i] = o;
    }
}

__global__ void layer_last_bucket_kernel(const int* __restrict__ bs, const int* __restrict__ packed,
                                         const float4* __restrict__ y, const float* __restrict__ dinv,
                                         const float* __restrict__ b,
                                         float* __restrict__ out, int N) {
    __shared__ float acc[BUCKET_SIZE * 3];
    for (int k = threadIdx.x; k < BUCKET_SIZE * 3; k += blockDim.x) acc[k] = 0.0f;
    __syncthreads();
    int beg = bs[blockIdx.x], end = bs[blockIdx.x + 1];
    int stride = blockDim.x;
    int k = beg + threadIdx.x;
    for (; k + 3 * stride < end; k += 4 * stride) {
        unsigned r0 = packed[k], r1 = packed[k + stride];
        unsigned r2 = packed[k + 2 * stride], r3 = packed[k + 3 * stride];
        float4 v0 = y[r0 & 0xFFFFFu], v1 = y[r1 & 0xFFFFFu];
        float4 v2 = y[r2 & 0xFFFFFu], v3 = y[r3 & 0xFFFFFu];
        int d0 = (r0 >> 20) * 3, d1 = (r1 >> 20) * 3, d2 = (r2 >> 20) * 3, d3 = (r3 >> 20) * 3;
        atomicAdd(&acc[d0 + 0], v0.x); atomicAdd(&acc[d0 + 1], v0.y); atomicAdd(&acc[d0 + 2], v0.z);
        atomicAdd(&acc[d1 + 0], v1.x); atomicAdd(&acc[d1 + 1], v1.y); atomicAdd(&acc[d1 + 2], v1.z);
        atomicAdd(&acc[d2 + 0], v2.x); atomicAdd(&acc[d2 + 1], v2.y); atomicAdd(&acc[d2 + 2], v2.z);
        atomicAdd(&acc[d3 + 0], v3.x); atomicAdd(&acc[d3 + 1], v3.y); atomicAdd(&acc[d3 + 2], v3.z);
    }
    for (; k < end; k += stride) {
        unsigned rec = (unsigned)packed[k];
        float4 v = y[rec & 0xFFFFFu];
        int dl = (rec >> 20) * 3;
        atomicAdd(&acc[dl + 0], v.x);
        atomicAdd(&acc[dl + 1], v.y);
        atomicAdd(&acc[dl + 2], v.z);
    }
    __syncthreads();
    int base = blockIdx.x << BUCKET_BITS;
    for (int j = threadIdx.x; j < BUCKET_SIZE; j += blockDim.x) {
        int i = base + j;
        if (i >= N) continue;
        float di = dinv[i];
        float4 yi = y[i];
        out[i * 3 + 0] = fmaxf(di * (acc[j * 3 + 0] + yi.x) + b[0], 0.0f);
        out[i * 3 + 1] = fmaxf(di * (acc[j * 3 + 1] + yi.y) + b[1], 0.0f);
        out[i * 3 + 2] = fmaxf(di * (acc[j * 3 + 2] + yi.z) + b[2], 0.0f);
    }
}

// ---------------- fallback (atomic scatter path, known-good R0) ----------------

__global__ void deg_kernel(const int* __restrict__ e, long long E,
                           const int* __restrict__ flag, float* __restrict__ deg) {
    const bool i64 = (*flag != 0);
    long long i = (long long)blockIdx.x * blockDim.x + threadIdx.x;
    const long long stride = (long long)gridDim.x * blockDim.x;
    for (; i < E; i += stride) {
        long long t = i64 ? (long long)e[2 * E + 2 * i] : (long long)e[E + i];
        atomicAdd(deg + t, 1.0f);
    }
}

__global__ void node_init_kernel(const float* __restrict__ x, const float* __restrict__ W1,
                                 float* __restrict__ deg_dinv, float* __restrict__ A, int N) {
    int i = blockIdx.x * blockDim.x + threadIdx.x;
    if (i >= N) return;
    float di = rsqrtf(deg_dinv[i] + 1.0f);
    deg_dinv[i] = di;
    float v = x[i] * di;
    A[i * 3 + 0] = v * W1[0];
    A[i * 3 + 1] = v * W1[1];
    A[i * 3 + 2] = v * W1[2];
}

__global__ void scatter_kernel(const int* __restrict__ e, long long E,
                               const int* __restrict__ flag,
                               const float* __restrict__ y, float* __restrict__ acc) {
    const bool i64 = (*flag != 0);
    long long i = (long long)blockIdx.x * blockDim.x + threadIdx.x;
    const long long stride = (long long)gridDim.x * blockDim.x;
    for (; i < E; i += stride) {
        int s, t;
        if (i64) { s = e[2 * i]; t = e[2 * E + 2 * i]; }
        else     { s = e[i];     t = e[E + i]; }
        atomicAdd(acc + (long long)t * 3 + 0, y[(long long)s * 3 + 0]);
        atomicAdd(acc + (long long)t * 3 + 1, y[(long long)s * 3 + 1]);
        atomicAdd(acc + (long long)t * 3 + 2, y[(long long)s * 3 + 2]);
    }
}

__global__ void finalize_mid_kernel(const float* __restrict__ dinv, const float* __restrict__ y,
                                    float* __restrict__ acc, const float* __restrict__ b,
                                    const float* __restrict__ Wn, int N) {
    int i = blockIdx.x * blockDim.x + threadIdx.x;
    if (i >= N) return;
    float di = dinv[i];
    float h0 = fmaxf(di * (acc[i * 3 + 0] + y[i * 3 + 0]) + b[0], 0.0f);
    float h1 = fmaxf(di * (acc[i * 3 + 1] + y[i * 3 + 1]) + b[1], 0.0f);
    float h2 = fmaxf(di * (acc[i * 3 + 2] + y[i * 3 + 2]) + b[2], 0.0f);
    float z0 = di * (h0 * Wn[0] + h1 * Wn[3] + h2 * Wn[6]);
    float z1 = di * (h0 * Wn[1] + h1 * Wn[4] + h2 * Wn[7]);
    float z2 = di * (h0 * Wn[2] + h1 * Wn[5] + h2 * Wn[8]);
    acc[i * 3 + 0] = z0;
    acc[i * 3 + 1] = z1;
    acc[i * 3 + 2] = z2;
}

__global__ void finalize_last_kernel(const float* __restrict__ dinv, const float* __restrict__ y,
                                     const float* __restrict__ acc, const float* __restrict__ b,
                                     float* __restrict__ out, int N) {
    int i = blockIdx.x * blockDim.x + threadIdx.x;
    if (i >= N) return;
    float di = dinv[i];
    out[i * 3 + 0] = fmaxf(di * (acc[i * 3 + 0] + y[i * 3 + 0]) + b[0], 0.0f);
    out[i * 3 + 1] = fmaxf(di * (acc[i * 3 + 1] + y[i * 3 + 1]) + b[1], 0.0f);
    out[i * 3 + 2] = fmaxf(di * (acc[i * 3 + 2] + y[i * 3 + 2]) + b[2], 0.0f);
}

// ---------------- launch ----------------

extern "C" void kernel_launch(void* const* d_in, const int* in_sizes, int n_in,
                              void* d_out, int out_size, void* d_ws, size_t ws_size,
                              hipStream_t stream) {
    const float* x  = (const float*)d_in[0];
    const int*   ei = (const int*)d_in[1];
    const float* W1 = (const float*)d_in[2];
    const float* b1 = (const float*)d_in[3];
    const float* W2 = (const float*)d_in[4];
    const float* b2 = (const float*)d_in[5];
    const float* W3 = (const float*)d_in[6];
    const float* b3 = (const float*)d_in[7];
    float* out = (float*)d_out;

    const long long N = in_sizes[0];
    const long long E = (long long)in_sizes[1] / 2;

    const int nbuck = (int)((N + BUCKET_SIZE - 1) >> BUCKET_BITS);
    const int nsub  = (int)((E + SUBCHUNK - 1) / SUBCHUNK);
    const int nsb   = (nsub + GROUP - 1) / GROUP;
    const int len   = nbuck * nsub;

    char* w = (char*)d_ws;
    size_t off = 0;
    auto alloc = [&](size_t bytes) -> char* {
        char* pp = w + off;
        off = (off + bytes + 255) & ~(size_t)255;
        return pp;
    };

    int*    flag   = (int*)alloc(4);
    int*    H      = (int*)alloc((size_t)len * 4);
    int*    bs     = (int*)alloc(((size_t)nbuck + 1) * 4);
    int*    packed = (int*)alloc((size_t)E * 4);
    float*  dinv   = (float*)alloc((size_t)N * 4);
    float*  p      = (float*)alloc((size_t)N * 4);
    float4* y2     = (float4*)alloc((size_t)N * 16);
    float4* y3     = (float4*)alloc((size_t)N * 16);

    const int nblk    = (int)((N + THREADS - 1) / THREADS);
    const int nb_scan = (len + SCAN_ELEMS - 1) / SCAN_ELEMS;

    if (off <= ws_size && N <= (1 << 20) && nbuck <= MAXBUCK) {
        detect_i64_kernel<<<1, 64, 0, stream>>>(ei, flag);
        hist_kernel<<<nsub, TPB_E, 0, stream>>>(ei, E, flag, nsub, nbuck, H);
        int* bsum = (int*)p;  // p not yet live; nb_scan ints << N floats
        scan1_kernel<<<nb_scan, SCAN_TPB, 0, stream>>>(H, len, bsum);
        scan2_kernel<<<1, 64, 0, stream>>>(bsum, nb_scan);
        scan3_kernel<<<nb_scan, SCAN_TPB, 0, stream>>>(H, len, bsum);
        bstart_kernel<<<(nbuck + THREADS) / THREADS, THREADS, 0, stream>>>(H, nsub, nbuck, E, bs);
        scatter_pack_kernel<<<nsb, TPB_E, 0, stream>>>(ei, E, flag, nsub, nbuck, H, packed);

        deg_init_kernel<<<nbuck, THREADS, 0, stream>>>(bs, packed, x, dinv, p, (int)N);
        layer1_bucket_kernel<<<nbuck, THREADS, 0, stream>>>(bs, packed, p, dinv, W1, b1, W2, y2, (int)N);
        layer_mid_bucket_kernel<<<nbuck, THREADS, 0, stream>>>(bs, packed, y2, dinv, b2, W3, y3, (int)N);
        layer_last_bucket_kernel<<<nbuck, THREADS, 0, stream>>>(bs, packed, y3, dinv, b3, out, (int)N);
    } else {
        // ---- fallback: atomic scatter path (proven R0) ----
        int*   fflag = (int*)w;
        float* fdinv = (float*)(w + 256);
        float* A     = fdinv + N;
        size_t need_full = 256 + (size_t)N * 4 + (size_t)N * 12 * 2;
        float* B = (ws_size >= need_full) ? (A + 3 * N) : out;
        const int eblk = 2048;

        detect_i64_kernel<<<1, 64, 0, stream>>>(ei, fflag);
        hipMemsetAsync(fdinv, 0, (size_t)N * 4, stream);
        deg_kernel<<<eblk, THREADS, 0, stream>>>(ei, E, fflag, fdinv);
        node_init_kernel<<<nblk, THREADS, 0, stream>>>(x, W1, fdinv, A, (int)N);

        hipMemsetAsync(B, 0, (size_t)N * 12, stream);
        scatter_kernel<<<eblk, THREADS, 0, stream>>>(ei, E, fflag, A, B);
        finalize_mid_kernel<<<nblk, THREADS, 0, stream>>>(fdinv, A, B, b1, W2, (int)N);

        hipMemsetAsync(A, 0, (size_t)N * 12, stream);
        scatter_kernel<<<eblk, THREADS, 0, stream>>>(ei, E, fflag, B, A);
        finalize_mid_kernel<<<nblk, THREADS, 0, stream>>>(fdinv, B, A, b2, W3, (int)N);

        hipMemsetAsync(B, 0, (size_t)N * 12, stream);
        scatter_kernel<<<eblk, THREADS, 0, stream>>>(ei, E, fflag, A, B);
        finalize_last_kernel<<<nblk, THREADS, 0, stream>>>(fdinv, A, B, b3, out, (int)N);
    }
}